// Round 7
// baseline (309.105 us; speedup 1.0000x reference)
//
#include <hip/hip_runtime.h>
#include <hip/hip_bf16.h>
#include <cstdint>

typedef __bf16 bf16_t;
typedef bf16_t bf16x8 __attribute__((ext_vector_type(8)));
typedef float f32x4 __attribute__((ext_vector_type(4)));

// B=4, S=4096, DIM=1024, H=16, HD=64, M=64
// QKV layout: [16384][3072] bf16, cols 0-1023 = Q', 1024-2047 = K', 2048-3071 = V

__device__ __forceinline__ void gload_lds16(const bf16_t* g, bf16_t* l) {
  __builtin_amdgcn_global_load_lds(
      (const __attribute__((address_space(1))) uint32_t*)g,
      (__attribute__((address_space(3))) uint32_t*)l, 16, 0, 0);
}

// ---------------- cast fp32 -> bf16 (vectorized, 8 elems/thread) ----------------
__global__ void cast_f32_bf16(const float* __restrict__ in, bf16_t* __restrict__ out, int n8) {
  int i = blockIdx.x * 256 + threadIdx.x;
  if (i < n8) {
    const f32x4* p = (const f32x4*)(in + (long)i * 8);
    f32x4 a = p[0], b = p[1];
    bf16x8 o;
#pragma unroll
    for (int j = 0; j < 4; ++j) { o[j] = (bf16_t)a[j]; o[j + 4] = (bf16_t)b[j]; }
    *(bf16x8*)(out + (long)i * 8) = o;
  }
}

__global__ void copy_f32(const float* __restrict__ in, float* __restrict__ out, int n) {
  int i = blockIdx.x * 256 + threadIdx.x;
  if (i < n) out[i] = in[i];
}

// ---------------- fold P into Wq/Wk:  WQP[h*64+m][k] = sum_d P[h][m][d]*W[h*64+d][k] ----------------
__global__ __launch_bounds__(256) void prep_wqk(
    const float* __restrict__ Wq, const float* __restrict__ bq,
    const float* __restrict__ Wk, const float* __restrict__ bk,
    const float* __restrict__ P,
    bf16_t* __restrict__ Wcat, float* __restrict__ bcat)
{
  int bid = blockIdx.x;
  int qk = bid >> 7, h = (bid >> 3) & 15, kt = bid & 7;
  const float* W = qk ? Wk : Wq;
  const float* bias = qk ? bk : bq;
  __shared__ float Pl[64 * 64];
  __shared__ float Wlt[128 * 68];
  int t = threadIdx.x;
  int k0 = kt * 128;
  for (int i = t * 4; i < 4096; i += 1024)
    *(f32x4*)&Pl[i] = *(const f32x4*)&P[h * 4096 + i];
  for (int fi = t; fi < 2048; fi += 256) {
    int row = fi >> 5;
    int c4 = fi & 31;
    f32x4 w = *(const f32x4*)&W[(long)(h * 64 + row) * 1024 + k0 + c4 * 4];
#pragma unroll
    for (int j = 0; j < 4; ++j) Wlt[(c4 * 4 + j) * 68 + row] = w[j];
  }
  __syncthreads();
  int kloc = t >> 1;
  int mh = (t & 1) * 32;
  for (int m = mh; m < mh + 32; ++m) {
    f32x4 s = {0.f, 0.f, 0.f, 0.f};
#pragma unroll
    for (int dd = 0; dd < 16; ++dd)
      s += (*(const f32x4*)&Pl[m * 64 + dd * 4]) * (*(const f32x4*)&Wlt[kloc * 68 + dd * 4]);
    float a = s[0] + s[1] + s[2] + s[3];
    Wcat[(long)(qk * 1024 + h * 64 + m) * 1024 + k0 + kloc] = (bf16_t)a;
  }
  if (kt == 0 && t < 64) {
    float a = 0.f;
    for (int d = 0; d < 64; ++d) a += Pl[t * 64 + d] * bias[h * 64 + d];
    bcat[qk * 1024 + h * 64 + t] = a;
  }
}

// ---------------- 256x256 GEMM, BK=64, 8 waves, 8-phase template -----------------
// C[M,N] = A[M,K] @ B[N,K]^T + bias.  EPI=1: bf16 out, relu*0.125 for gcol<2048.
// EPI=2: fp32 out.
//
// LDS 128KB: A[2 buf][2 half:128rows x 64k] + B same, XOR-involution kq^(row&7)
// on global source and ds_read (r1 algebra, measured 0 conflicts).
// Per tile, 4 phases (quadrants (0,0),(1,0),(1,1),(0,1)):
//   {ds_reads; stage; [lgkmcnt(8)]; s_barrier; lgkmcnt(0); 16 MFMA; s_barrier}
// Stages: ph1 B1(t+1)->other buf; ph3 A0(t+2); ph4 A1(t+2)+B0(t+2) -> this buf
// (each region's last read is >=1 phase-barrier before its re-stage).
// vmcnt(6) at tile end retires exactly tile t+1's 4 halves (issued 1 tile ago).
#define VMW(N) asm volatile("s_waitcnt vmcnt(" #N ")" ::: "memory")
#define LGK(N) asm volatile("s_waitcnt lgkmcnt(" #N ")" ::: "memory")
#define SBAR() __builtin_amdgcn_s_barrier()

#define STAGE_A(P, H, KT) {                                                  \
  const bf16_t* s_ = A + aG + (long)(H) * 128 * lda + (KT);                  \
  gload_lds16(s_, &smem[(P)*16384 + (H)*8192 + dst8]);                       \
  gload_lds16(s_ + 64 * lda, &smem[(P)*16384 + (H)*8192 + 4096 + dst8]); }

#define STAGE_B(P, H, KT) {                                                  \
  const bf16_t* s_ = Bm + bG + (long)(H) * 128 * ldb + (KT);                 \
  gload_lds16(s_, &smem[32768 + (P)*16384 + (H)*8192 + dst8]);               \
  gload_lds16(s_ + 64 * ldb, &smem[32768 + (P)*16384 + (H)*8192 + 4096 + dst8]); }

#define RD_A(dst, P, QM)                                                     \
  _Pragma("unroll") for (int i = 0; i < 4; ++i) {                            \
    dst[i][0] = *(const bf16x8*)&smem[(P)*16384 + aR + ((QM)*64 + i*16)*64 + e0]; \
    dst[i][1] = *(const bf16x8*)&smem[(P)*16384 + aR + ((QM)*64 + i*16)*64 + e1]; }

#define RD_B(dst, P, QN)                                                     \
  _Pragma("unroll") for (int j = 0; j < 2; ++j) {                            \
    dst[j][0] = *(const bf16x8*)&smem[32768 + (P)*16384 + bR + ((QN)*32 + j*16)*64 + e0]; \
    dst[j][1] = *(const bf16x8*)&smem[32768 + (P)*16384 + bR + ((QN)*32 + j*16)*64 + e1]; }

#define MFMA16(MB, NB, AF, BF) {                                             \
  __builtin_amdgcn_s_setprio(1);                                             \
  _Pragma("unroll") for (int i = 0; i < 4; ++i)                              \
    _Pragma("unroll") for (int j = 0; j < 2; ++j) {                          \
      acc[(MB)+i][(NB)+j] = __builtin_amdgcn_mfma_f32_16x16x32_bf16(AF[i][0], BF[j][0], acc[(MB)+i][(NB)+j], 0, 0, 0); \
      acc[(MB)+i][(NB)+j] = __builtin_amdgcn_mfma_f32_16x16x32_bf16(AF[i][1], BF[j][1], acc[(MB)+i][(NB)+j], 0, 0, 0); \
    }                                                                        \
  __builtin_amdgcn_s_setprio(0); }

#define TILE(P, KT1, KT2, SB1, S2, WN) {                                     \
  RD_A(afr0, P, 0); RD_B(bfr0, P, 0);                                        \
  if (SB1) STAGE_B((P)^1, 1, KT1);                                           \
  LGK(8); SBAR(); LGK(0);                                                    \
  MFMA16(0, 0, afr0, bfr0);                                                  \
  SBAR();                                                                    \
  RD_A(afr1, P, 1);                                                          \
  SBAR(); LGK(0);                                                            \
  MFMA16(4, 0, afr1, bfr0);                                                  \
  SBAR();                                                                    \
  RD_B(bfr1, P, 1);                                                          \
  if (S2) STAGE_A(P, 0, KT2);                                                \
  SBAR(); LGK(0);                                                            \
  MFMA16(4, 2, afr1, bfr1);                                                  \
  SBAR();                                                                    \
  if (S2) { STAGE_A(P, 1, KT2); STAGE_B(P, 0, KT2); }                        \
  SBAR();                                                                    \
  MFMA16(0, 2, afr0, bfr1);                                                  \
  VMW(WN); SBAR();                                                           \
}

template <int EPI>
__global__ __launch_bounds__(512, 2) void gemm256(
    const bf16_t* __restrict__ A, int lda,
    const bf16_t* __restrict__ B0, int ldb,
    const float* __restrict__ bias,
    void* __restrict__ Cv, int ldc,
    int K, int ncols, int cpx,
    int rows_per_batch, long bstride)
{
  __shared__ alignas(16) bf16_t smem[65536];   // A: [0,32768), B: [32768,65536)

  // XCD-aware block swizzle (nwg % 8 == 0 guaranteed by caller)
  const int lin = blockIdx.x;
  const int wgid = (lin & 7) * cpx + (lin >> 3);
  const int row0 = (wgid / ncols) * 256;
  const int col0 = (wgid % ncols) * 256;

  const int tid = threadIdx.x;
  const int w = tid >> 6, l = tid & 63;
  const int wr = w >> 2, wc = w & 3;          // wave grid 2 (M) x 4 (N)
  const int llo = l & 15, lhi = l >> 4;
  const int x7 = llo & 7;

  const bf16_t* Bm = B0 + (long)(row0 / rows_per_batch) * bstride;

  // staging: chunk c0 = tid (rows 0-63 of half), c1 = tid+512 (rows 64-127);
  // source k-chunk pre-swizzled with involution kq ^ (row&7); row&7 same for both.
  const int r0 = tid >> 3;
  const int kq0 = (tid & 7) ^ (r0 & 7);
  const long aG = (long)(row0 + r0) * lda + kq0 * 8;
  const long bG = (long)(col0 + r0) * ldb + kq0 * 8;
  const int dst8 = tid * 8;

  // ds_read addressing: elem = ρ*64 + (kq ^ (ρ&7))*8, ρ&7 == llo&7
  const int aR = wr * 8192 + llo * 64;
  const int bR = (wc >> 1) * 8192 + (wc & 1) * 4096 + llo * 64;
  const int e0 = ((lhi) ^ x7) * 8;
  const int e1 = ((4 + lhi) ^ x7) * 8;

  f32x4 acc[8][4] = {};
  bf16x8 afr0[4][2], afr1[4][2], bfr0[2][2], bfr1[2][2];
  const int NT = K >> 6;   // even, >= 4

  // prologue: t0 full (4 halves) + t1's A0,A1,B0 (3 halves); retire t0
  STAGE_A(0, 0, 0L); STAGE_A(0, 1, 0L); STAGE_B(0, 0, 0L); STAGE_B(0, 1, 0L);
  STAGE_A(1, 0, 64L); STAGE_A(1, 1, 64L); STAGE_B(1, 0, 64L);
  VMW(6); SBAR();

  int t = 0;
  for (; t + 4 <= NT; t += 2) {
    TILE(0, (long)(t + 1) * 64, (long)(t + 2) * 64, 1, 1, 6);
    TILE(1, (long)(t + 2) * 64, (long)(t + 3) * 64, 1, 1, 6);
  }
  TILE(0, (long)(NT - 1) * 64, 0L, 1, 0, 0);   // tile NT-2: stage B1(NT-1), drain
  TILE(1, 0L, 0L, 0, 0, 0);                    // tile NT-1: no staging

  // epilogue: C/D layout col=lane&15, row=(lane>>4)*4+j; quadrant remap:
  // acc[qm*4+i][qn*2+j] -> rows wr*128+qm*64+i*16, cols wc*64+qn*32+j*16
#pragma unroll
  for (int ni = 0; ni < 4; ++ni) {
    const int gcol = col0 + wc * 64 + (ni >> 1) * 32 + (ni & 1) * 16 + llo;
    const float bz = bias[gcol];
#pragma unroll
    for (int mi = 0; mi < 8; ++mi) {
      const int grow0 = row0 + wr * 128 + (mi >> 2) * 64 + (mi & 3) * 16 + lhi * 4;
#pragma unroll
      for (int j = 0; j < 4; ++j) {
        float v = acc[mi][ni][j] + bz;
        if constexpr (EPI == 1) { if (gcol < 2048) v = fmaxf(v, 0.f) * 0.125f; }
        if constexpr (EPI == 2)
          ((float*)Cv)[(long)(grow0 + j) * ldc + gcol] = v;
        else
          ((bf16_t*)Cv)[(long)(grow0 + j) * ldc + gcol] = (bf16_t)v;
      }
    }
  }
}

// ---------------- kv partial: kv[b,h,m,d] = sum_s K'[b,s,h,m]*V[b,s,h,d] ----------------
__global__ __launch_bounds__(256) void kv_partial(
    const bf16_t* __restrict__ QKV, float* __restrict__ kvpart)
{
  int bh = blockIdx.x;
  int split = blockIdx.y;
  int b = bh >> 4, h = bh & 15;
  __shared__ alignas(16) bf16_t Kt[64 * 32];
  __shared__ alignas(16) bf16_t Vt[64 * 32];
  int t = threadIdx.x;
  int wv = t >> 6, lane = t & 63, lhi = lane >> 4, llo = lane & 15;
  int r = t >> 3;
  int c = (t & 7) * 8;
  f32x4 acc[4] = {};
  long rowbase = ((long)b * 4096 + split * 512) * 3072 + h * 64 + c;
  for (int sc = 0; sc < 16; ++sc) {
    long off = rowbase + (long)(sc * 32 + r) * 3072;
    bf16x8 kk = *(const bf16x8*)(QKV + off + 1024);
    bf16x8 vvv = *(const bf16x8*)(QKV + off + 2048);
#pragma unroll
    for (int j = 0; j < 8; ++j) {
      Kt[(c + j) * 32 + r] = kk[j];
      Vt[(c + j) * 32 + r] = vvv[j];
    }
    __syncthreads();
    bf16x8 a = *(const bf16x8*)&Kt[(wv * 16 + llo) * 32 + lhi * 8];
#pragma unroll
    for (int ni = 0; ni < 4; ++ni) {
      bf16x8 bb = *(const bf16x8*)&Vt[(ni * 16 + llo) * 32 + lhi * 8];
      acc[ni] = __builtin_amdgcn_mfma_f32_16x16x32_bf16(a, bb, acc[ni], 0, 0, 0);
    }
    __syncthreads();
  }
#pragma unroll
  for (int ni = 0; ni < 4; ++ni)
#pragma unroll
    for (int j = 0; j < 4; ++j) {
      int m = wv * 16 + lhi * 4 + j;
      int d = ni * 16 + llo;
      kvpart[((long)split * 64 + bh) * 4096 + m * 64 + d] = acc[ni][j];
    }
}

__global__ void kv_reduce(const float* __restrict__ part, float* __restrict__ kv) {
  int i = blockIdx.x * 256 + threadIdx.x;
  float s = 0.f;
#pragma unroll
  for (int sp = 0; sp < 8; ++sp) s += part[sp * 262144 + i];
  kv[i] = s;
}

// ---------------- WcombT[b][n][h*64+m] = sum_d kv[b,h,m,d] * Wo[n][h*64+d] ----------------
__global__ __launch_bounds__(256) void wcombt_kernel(
    const float* __restrict__ kv, const float* __restrict__ Wo,
    bf16_t* __restrict__ WcT)
{
  int nt = blockIdx.x, h = blockIdx.y, b = blockIdx.z;
  __shared__ float kvs[4096];
  int t = threadIdx.x;
  for (int i = t * 4; i < 4096; i += 1024)
    *(f32x4*)&kvs[i] = *(const f32x4*)&kv[((long)b * 16 + h) * 4096 + i];
  __syncthreads();
  int n = nt * 128 + (t >> 1);
  int mh = (t & 1) * 32;
  f32x4 wo[16];
#pragma unroll
  for (int dd = 0; dd < 16; ++dd) wo[dd] = *(const f32x4*)&Wo[(long)n * 1024 + h * 64 + dd * 4];
  for (int m = mh; m < mh + 32; ++m) {
    f32x4 s = {0.f, 0.f, 0.f, 0.f};
#pragma unroll
    for (int dd = 0; dd < 16; ++dd)
      s += (*(const f32x4*)&kvs[m * 64 + dd * 4]) * wo[dd];
    WcT[((long)b * 1024 + n) * 1024 + h * 64 + m] = (bf16_t)(s[0] + s[1] + s[2] + s[3]);
  }
}

// ---------------- launch ----------------
extern "C" void kernel_launch(void* const* d_in, const int* in_sizes, int n_in,
                              void* d_out, int out_size, void* d_ws, size_t ws_size,
                              hipStream_t stream) {
  (void)in_sizes; (void)n_in; (void)out_size; (void)ws_size;
  const float* x  = (const float*)d_in[0];
  const float* Wq = (const float*)d_in[1];
  const float* bq = (const float*)d_in[2];
  const float* Wk = (const float*)d_in[3];
  const float* bk = (const float*)d_in[4];
  const float* Wv = (const float*)d_in[5];
  const float* bv = (const float*)d_in[6];
  const float* Wo = (const float*)d_in[7];
  const float* bo = (const float*)d_in[8];
  const float* P  = (const float*)d_in[9];
  float* out = (float*)d_out;

  char* ws = (char*)d_ws;
  bf16_t* xb     = (bf16_t*)(ws + 0);            // 32 MB
  bf16_t* QKV    = (bf16_t*)(ws + 33554432);     // 96 MB
  bf16_t* Wcat   = (bf16_t*)(ws + 134217728);    // 6 MB
  float*  bcat   = (float*) (ws + 140509184);    // 12 KB
  float*  kvpart = (float*) (ws + 140521472);    // 8 MB
  float*  kvbuf  = (float*) (ws + 148910080);    // 1 MB
  bf16_t* WcT    = (bf16_t*)(ws + 149958656);    // 8 MB

  // 1. casts + weight prep
  cast_f32_bf16<<<8192, 256, 0, stream>>>(x, xb, 2097152);
  cast_f32_bf16<<<512, 256, 0, stream>>>(Wv, Wcat + (size_t)2048 * 1024, 131072);
  copy_f32<<<4, 256, 0, stream>>>(bv, bcat + 2048, 1024);
  prep_wqk<<<256, 256, 0, stream>>>(Wq, bq, Wk, bk, P, Wcat, bcat);

  // 2. fused Q'/K'/V GEMM: [16384,1024] x [3072,1024]^T -> [16384,3072]
  //    grid 64 x 12 = 768 blocks (768 % 8 == 0), cpx = 96
  gemm256<1><<<768, 512, 0, stream>>>(
      xb, 1024, Wcat, 1024, bcat, QKV, 3072, 1024, 12, 96, 1 << 30, 0);

  // 3. kv = K'^T @ V per (b,h), 8-way split over s, then reduce
  kv_partial<<<dim3(64, 8), 256, 0, stream>>>(QKV, kvpart);
  kv_reduce<<<1024, 256, 0, stream>>>(kvpart, kvbuf);

  // 4. fold kv into Wo: WcombT per batch
  wcombt_kernel<<<dim3(8, 16, 4), 256, 0, stream>>>(kvbuf, Wo, WcT);

  // 5. out = Q' @ WcombT[b]^T + bo  (fp32 out)
  //    grid 64 x 4 = 256 blocks, cpx = 32
  gemm256<2><<<256, 512, 0, stream>>>(
      QKV, 3072, WcT, 1024, bo, out, 1024, 1024, 4, 32, 4096, (long)1024 * 1024);
}

// Round 8
// 233.828 us; speedup vs baseline: 1.3219x; 1.3219x over previous
//
#include <hip/hip_runtime.h>
#include <hip/hip_bf16.h>
#include <cstdint>

typedef __bf16 bf16_t;
typedef bf16_t bf16x8 __attribute__((ext_vector_type(8)));
typedef float f32x4 __attribute__((ext_vector_type(4)));

// B=4, S=4096, DIM=1024, H=16, HD=64, M=64
// QKV layout: [16384][3072] bf16, cols 0-1023 = Q', 1024-2047 = K', 2048-3071 = V

__device__ __forceinline__ void gload_lds16(const bf16_t* g, bf16_t* l) {
  __builtin_amdgcn_global_load_lds(
      (const __attribute__((address_space(1))) uint32_t*)g,
      (__attribute__((address_space(3))) uint32_t*)l, 16, 0, 0);
}

// ---------------- merged prep: cast x, cast Wv, copy bv (one launch) ------------
__global__ void prep_misc(const float* __restrict__ x, const float* __restrict__ Wv,
                          const float* __restrict__ bv,
                          bf16_t* __restrict__ xb, bf16_t* __restrict__ WvO,
                          float* __restrict__ bcat) {
  int b = blockIdx.x, t = threadIdx.x;
  if (b < 8192) {
    long i = (long)b * 256 + t;
    const f32x4* p = (const f32x4*)(x + i * 8);
    f32x4 a = p[0], c = p[1];
    bf16x8 o;
#pragma unroll
    for (int j = 0; j < 4; ++j) { o[j] = (bf16_t)a[j]; o[j + 4] = (bf16_t)c[j]; }
    *(bf16x8*)(xb + i * 8) = o;
  } else if (b < 8704) {
    long i = (long)(b - 8192) * 256 + t;
    const f32x4* p = (const f32x4*)(Wv + i * 8);
    f32x4 a = p[0], c = p[1];
    bf16x8 o;
#pragma unroll
    for (int j = 0; j < 4; ++j) { o[j] = (bf16_t)a[j]; o[j + 4] = (bf16_t)c[j]; }
    *(bf16x8*)(WvO + i * 8) = o;
  } else {
    *(f32x4*)&bcat[2048 + t * 4] = *(const f32x4*)&bv[t * 4];
  }
}

// ---------------- fold P into Wq/Wk:  WQP[h*64+m][k] = sum_d P[h][m][d]*W[h*64+d][k] ----------------
__global__ __launch_bounds__(256) void prep_wqk(
    const float* __restrict__ Wq, const float* __restrict__ bq,
    const float* __restrict__ Wk, const float* __restrict__ bk,
    const float* __restrict__ P,
    bf16_t* __restrict__ Wcat, float* __restrict__ bcat)
{
  int bid = blockIdx.x;
  int qk = bid >> 7, h = (bid >> 3) & 15, kt = bid & 7;
  const float* W = qk ? Wk : Wq;
  const float* bias = qk ? bk : bq;
  __shared__ float Pl[64 * 64];
  __shared__ float Wlt[128 * 68];
  int t = threadIdx.x;
  int k0 = kt * 128;
  for (int i = t * 4; i < 4096; i += 1024)
    *(f32x4*)&Pl[i] = *(const f32x4*)&P[h * 4096 + i];
  for (int fi = t; fi < 2048; fi += 256) {
    int row = fi >> 5;
    int c4 = fi & 31;
    f32x4 w = *(const f32x4*)&W[(long)(h * 64 + row) * 1024 + k0 + c4 * 4];
#pragma unroll
    for (int j = 0; j < 4; ++j) Wlt[(c4 * 4 + j) * 68 + row] = w[j];
  }
  __syncthreads();
  int kloc = t >> 1;
  int mh = (t & 1) * 32;
  for (int m = mh; m < mh + 32; ++m) {
    f32x4 s = {0.f, 0.f, 0.f, 0.f};
#pragma unroll
    for (int dd = 0; dd < 16; ++dd)
      s += (*(const f32x4*)&Pl[m * 64 + dd * 4]) * (*(const f32x4*)&Wlt[kloc * 68 + dd * 4]);
    float a = s[0] + s[1] + s[2] + s[3];
    Wcat[(long)(qk * 1024 + h * 64 + m) * 1024 + k0 + kloc] = (bf16_t)a;
  }
  if (kt == 0 && t < 64) {
    float a = 0.f;
    for (int d = 0; d < 64; ++d) a += Pl[t * 64 + d] * bias[h * 64 + d];
    bcat[qk * 1024 + h * 64 + t] = a;
  }
}

// ---------------- 256x256 GEMM (r1-exact): BK=64, 8 waves, 1 sync per K-tile -----
template <int EPI>
__global__ __launch_bounds__(512, 2) void gemm256(
    const bf16_t* __restrict__ A, int lda,
    const bf16_t* __restrict__ B0, int ldb,
    const float* __restrict__ bias,
    void* __restrict__ Cv, int ldc,
    int K, int ncols, int cpx,
    int rows_per_batch, long bstride)
{
  __shared__ bf16_t sA[2][16384];
  __shared__ bf16_t sB[2][16384];

  const int lin = blockIdx.x;
  const int wgid = (lin & 7) * cpx + (lin >> 3);
  const int row0 = (wgid / ncols) * 256;
  const int col0 = (wgid % ncols) * 256;

  const int tid = threadIdx.x;
  const int w = tid >> 6, l = tid & 63;
  const int wr = w >> 2, wc = w & 3;
  const int llo = l & 15, lhi = l >> 4;
  const int x7 = llo & 7;

  const bf16_t* Bm = B0 + (long)(row0 / rows_per_batch) * bstride;

  long a_off[4], b_off[4];
#pragma unroll
  for (int i = 0; i < 4; ++i) {
    int c = i * 512 + tid;
    int r = c >> 3;
    int kqs = (c & 7) ^ (r & 7);
    a_off[i] = (long)(row0 + r) * lda + kqs * 8;
    b_off[i] = (long)(col0 + r) * ldb + kqs * 8;
  }
  const int ldst = tid * 8;

  const int aoff0 = ((lhi)     ^ x7) * 8;
  const int aoff1 = ((lhi + 4) ^ x7) * 8;
  const int abase = (wr * 128 + llo) * 64;
  const int bbase = (wc * 64 + llo) * 64;

  f32x4 acc[8][4] = {};
  const int NT = K >> 6;

#pragma unroll
  for (int i = 0; i < 4; ++i) {
    gload_lds16(A + a_off[i], &sA[0][i * 4096 + ldst]);
    gload_lds16(Bm + b_off[i], &sB[0][i * 4096 + ldst]);
  }
  __syncthreads();

#define TILE_BODY(PC, PN, T)                                                            \
  {                                                                                     \
    bf16x8 bfr[4][2], afr[4][2];                                                        \
    _Pragma("unroll") for (int ni = 0; ni < 4; ++ni) {                                  \
      bfr[ni][0] = *(const bf16x8*)&sB[PC][bbase + ni * 1024 + aoff0];                  \
      bfr[ni][1] = *(const bf16x8*)&sB[PC][bbase + ni * 1024 + aoff1];                  \
    }                                                                                   \
    _Pragma("unroll") for (int mi = 0; mi < 4; ++mi) {                                  \
      afr[mi][0] = *(const bf16x8*)&sA[PC][abase + mi * 1024 + aoff0];                  \
      afr[mi][1] = *(const bf16x8*)&sA[PC][abase + mi * 1024 + aoff1];                  \
    }                                                                                   \
    if ((T) + 1 < NT) {                                                                 \
      long ks = (long)((T) + 1) * 64;                                                   \
      _Pragma("unroll") for (int i = 0; i < 4; ++i) {                                   \
        gload_lds16(A + a_off[i] + ks, &sA[PN][i * 4096 + ldst]);                       \
        gload_lds16(Bm + b_off[i] + ks, &sB[PN][i * 4096 + ldst]);                      \
      }                                                                                 \
    }                                                                                   \
    __builtin_amdgcn_s_setprio(1);                                                      \
    _Pragma("unroll") for (int mi = 0; mi < 4; ++mi)                                    \
      _Pragma("unroll") for (int ni = 0; ni < 4; ++ni) {                                \
        acc[mi][ni] = __builtin_amdgcn_mfma_f32_16x16x32_bf16(afr[mi][0], bfr[ni][0], acc[mi][ni], 0, 0, 0); \
        acc[mi][ni] = __builtin_amdgcn_mfma_f32_16x16x32_bf16(afr[mi][1], bfr[ni][1], acc[mi][ni], 0, 0, 0); \
      }                                                                                 \
    __builtin_amdgcn_s_setprio(0);                                                      \
    _Pragma("unroll") for (int mi = 0; mi < 4; ++mi) {                                  \
      afr[mi][0] = *(const bf16x8*)&sA[PC][abase + (mi + 4) * 1024 + aoff0];            \
      afr[mi][1] = *(const bf16x8*)&sA[PC][abase + (mi + 4) * 1024 + aoff1];            \
    }                                                                                   \
    __builtin_amdgcn_s_setprio(1);                                                      \
    _Pragma("unroll") for (int mi = 0; mi < 4; ++mi)                                    \
      _Pragma("unroll") for (int ni = 0; ni < 4; ++ni) {                                \
        acc[mi + 4][ni] = __builtin_amdgcn_mfma_f32_16x16x32_bf16(afr[mi][0], bfr[ni][0], acc[mi + 4][ni], 0, 0, 0); \
        acc[mi + 4][ni] = __builtin_amdgcn_mfma_f32_16x16x32_bf16(afr[mi][1], bfr[ni][1], acc[mi + 4][ni], 0, 0, 0); \
      }                                                                                 \
    __builtin_amdgcn_s_setprio(0);                                                      \
    __syncthreads();                                                                    \
  }

  for (int t = 0; t < NT; t += 2) {
    TILE_BODY(0, 1, t);
    TILE_BODY(1, 0, t + 1);
  }
#undef TILE_BODY

#pragma unroll
  for (int ni = 0; ni < 4; ++ni) {
    const int gcol = col0 + wc * 64 + ni * 16 + llo;
    const float bz = bias[gcol];
#pragma unroll
    for (int mi = 0; mi < 8; ++mi) {
      const int grow0 = row0 + wr * 128 + mi * 16 + lhi * 4;
#pragma unroll
      for (int j = 0; j < 4; ++j) {
        float v = acc[mi][ni][j] + bz;
        if constexpr (EPI == 1) { if (gcol < 2048) v = fmaxf(v, 0.f) * 0.125f; }
        if constexpr (EPI == 2)
          ((float*)Cv)[(long)(grow0 + j) * ldc + gcol] = v;
        else
          ((bf16_t*)Cv)[(long)(grow0 + j) * ldc + gcol] = (bf16_t)v;
      }
    }
  }
}

// ---------------- 128x128 GEMM: same r1 loop, 64KB LDS -> 2 blocks/CU ------------
// fp32 out + bias. Wave grid 2M x 4N, per-wave 64x32, acc[4][2].
__global__ __launch_bounds__(512, 4) void gemm128(
    const bf16_t* __restrict__ A, int lda,
    const bf16_t* __restrict__ B0, int ldb,
    const float* __restrict__ bias,
    float* __restrict__ C, int ldc,
    int K, int ncols, int cpx,
    int rows_per_batch, long bstride)
{
  __shared__ bf16_t sA[2][8192];
  __shared__ bf16_t sB[2][8192];

  const int lin = blockIdx.x;
  const int wgid = (lin & 7) * cpx + (lin >> 3);
  const int row0 = (wgid / ncols) * 128;
  const int col0 = (wgid % ncols) * 128;

  const int tid = threadIdx.x;
  const int w = tid >> 6, l = tid & 63;
  const int wr = w >> 2, wc = w & 3;
  const int llo = l & 15, lhi = l >> 4;
  const int x7 = llo & 7;

  const bf16_t* Bm = B0 + (long)(row0 / rows_per_batch) * bstride;

  // staging: 1024 chunks of 8 bf16; chunk c: row=c>>3 (0..127), kq=(c&7)^(row&7)
  long a_off[2], b_off[2];
#pragma unroll
  for (int i = 0; i < 2; ++i) {
    int c = i * 512 + tid;
    int r = c >> 3;
    int kqs = (c & 7) ^ (r & 7);
    a_off[i] = (long)(row0 + r) * lda + kqs * 8;
    b_off[i] = (long)(col0 + r) * ldb + kqs * 8;
  }
  const int ldst = tid * 8;

  const int aoff0 = ((lhi)     ^ x7) * 8;
  const int aoff1 = ((lhi + 4) ^ x7) * 8;
  const int abase = (wr * 64 + llo) * 64;
  const int bbase = (wc * 32 + llo) * 64;

  f32x4 acc[4][2] = {};
  const int NT = K >> 6;

#pragma unroll
  for (int i = 0; i < 2; ++i) {
    gload_lds16(A + a_off[i], &sA[0][i * 4096 + ldst]);
    gload_lds16(Bm + b_off[i], &sB[0][i * 4096 + ldst]);
  }
  __syncthreads();

#define TILE128(PC, PN, T)                                                              \
  {                                                                                     \
    bf16x8 bfr[2][2], afr[4][2];                                                        \
    _Pragma("unroll") for (int ni = 0; ni < 2; ++ni) {                                  \
      bfr[ni][0] = *(const bf16x8*)&sB[PC][bbase + ni * 1024 + aoff0];                  \
      bfr[ni][1] = *(const bf16x8*)&sB[PC][bbase + ni * 1024 + aoff1];                  \
    }                                                                                   \
    _Pragma("unroll") for (int mi = 0; mi < 4; ++mi) {                                  \
      afr[mi][0] = *(const bf16x8*)&sA[PC][abase + mi * 1024 + aoff0];                  \
      afr[mi][1] = *(const bf16x8*)&sA[PC][abase + mi * 1024 + aoff1];                  \
    }                                                                                   \
    if ((T) + 1 < NT) {                                                                 \
      long ks = (long)((T) + 1) * 64;                                                   \
      _Pragma("unroll") for (int i = 0; i < 2; ++i) {                                   \
        gload_lds16(A + a_off[i] + ks, &sA[PN][i * 4096 + ldst]);                       \
        gload_lds16(Bm + b_off[i] + ks, &sB[PN][i * 4096 + ldst]);                      \
      }                                                                                 \
    }                                                                                   \
    __builtin_amdgcn_s_setprio(1);                                                      \
    _Pragma("unroll") for (int mi = 0; mi < 4; ++mi)                                    \
      _Pragma("unroll") for (int ni = 0; ni < 2; ++ni) {                                \
        acc[mi][ni] = __builtin_amdgcn_mfma_f32_16x16x32_bf16(afr[mi][0], bfr[ni][0], acc[mi][ni], 0, 0, 0); \
        acc[mi][ni] = __builtin_amdgcn_mfma_f32_16x16x32_bf16(afr[mi][1], bfr[ni][1], acc[mi][ni], 0, 0, 0); \
      }                                                                                 \
    __builtin_amdgcn_s_setprio(0);                                                      \
    __syncthreads();                                                                    \
  }

  for (int t = 0; t < NT; t += 2) {
    TILE128(0, 1, t);
    TILE128(1, 0, t + 1);
  }
#undef TILE128

#pragma unroll
  for (int ni = 0; ni < 2; ++ni) {
    const int gcol = col0 + wc * 32 + ni * 16 + llo;
    const float bz = bias[gcol];
#pragma unroll
    for (int mi = 0; mi < 4; ++mi) {
      const int grow0 = row0 + wr * 64 + mi * 16 + lhi * 4;
#pragma unroll
      for (int j = 0; j < 4; ++j)
        C[(long)(grow0 + j) * ldc + gcol] = acc[mi][ni][j] + bz;
    }
  }
}

// ---------------- kv partial: kv[b,h,m,d] = sum_s K'[b,s,h,m]*V[b,s,h,d] ----------------
__global__ __launch_bounds__(256) void kv_partial(
    const bf16_t* __restrict__ QKV, float* __restrict__ kvpart)
{
  int bh = blockIdx.x;
  int split = blockIdx.y;
  int b = bh >> 4, h = bh & 15;
  __shared__ alignas(16) bf16_t Kt[64 * 32];
  __shared__ alignas(16) bf16_t Vt[64 * 32];
  int t = threadIdx.x;
  int wv = t >> 6, lane = t & 63, lhi = lane >> 4, llo = lane & 15;
  int r = t >> 3;
  int c = (t & 7) * 8;
  f32x4 acc[4] = {};
  long rowbase = ((long)b * 4096 + split * 512) * 3072 + h * 64 + c;
  for (int sc = 0; sc < 16; ++sc) {
    long off = rowbase + (long)(sc * 32 + r) * 3072;
    bf16x8 kk = *(const bf16x8*)(QKV + off + 1024);
    bf16x8 vvv = *(const bf16x8*)(QKV + off + 2048);
#pragma unroll
    for (int j = 0; j < 8; ++j) {
      Kt[(c + j) * 32 + r] = kk[j];
      Vt[(c + j) * 32 + r] = vvv[j];
    }
    __syncthreads();
    bf16x8 a = *(const bf16x8*)&Kt[(wv * 16 + llo) * 32 + lhi * 8];
#pragma unroll
    for (int ni = 0; ni < 4; ++ni) {
      bf16x8 bb = *(const bf16x8*)&Vt[(ni * 16 + llo) * 32 + lhi * 8];
      acc[ni] = __builtin_amdgcn_mfma_f32_16x16x32_bf16(a, bb, acc[ni], 0, 0, 0);
    }
    __syncthreads();
  }
#pragma unroll
  for (int ni = 0; ni < 4; ++ni)
#pragma unroll
    for (int j = 0; j < 4; ++j) {
      int m = wv * 16 + lhi * 4 + j;
      int d = ni * 16 + llo;
      kvpart[((long)split * 64 + bh) * 4096 + m * 64 + d] = acc[ni][j];
    }
}

__global__ void kv_reduce(const float* __restrict__ part, float* __restrict__ kv) {
  int i = blockIdx.x * 256 + threadIdx.x;
  float s = 0.f;
#pragma unroll
  for (int sp = 0; sp < 8; ++sp) s += part[sp * 262144 + i];
  kv[i] = s;
}

// ---------------- WcombT[b][n][h*64+m] = sum_d kv[b,h,m,d] * Wo[n][h*64+d] ----------------
__global__ __launch_bounds__(256) void wcombt_kernel(
    const float* __restrict__ kv, const float* __restrict__ Wo,
    bf16_t* __restrict__ WcT)
{
  int nt = blockIdx.x, h = blockIdx.y, b = blockIdx.z;
  __shared__ float kvs[4096];
  int t = threadIdx.x;
  for (int i = t * 4; i < 4096; i += 1024)
    *(f32x4*)&kvs[i] = *(const f32x4*)&kv[((long)b * 16 + h) * 4096 + i];
  __syncthreads();
  int n = nt * 128 + (t >> 1);
  int mh = (t & 1) * 32;
  f32x4 wo[16];
#pragma unroll
  for (int dd = 0; dd < 16; ++dd) wo[dd] = *(const f32x4*)&Wo[(long)n * 1024 + h * 64 + dd * 4];
  for (int m = mh; m < mh + 32; ++m) {
    f32x4 s = {0.f, 0.f, 0.f, 0.f};
#pragma unroll
    for (int dd = 0; dd < 16; ++dd)
      s += (*(const f32x4*)&kvs[m * 64 + dd * 4]) * wo[dd];
    WcT[((long)b * 1024 + n) * 1024 + h * 64 + m] = (bf16_t)(s[0] + s[1] + s[2] + s[3]);
  }
}

// ---------------- launch ----------------
extern "C" void kernel_launch(void* const* d_in, const int* in_sizes, int n_in,
                              void* d_out, int out_size, void* d_ws, size_t ws_size,
                              hipStream_t stream) {
  (void)in_sizes; (void)n_in; (void)out_size; (void)ws_size;
  const float* x  = (const float*)d_in[0];
  const float* Wq = (const float*)d_in[1];
  const float* bq = (const float*)d_in[2];
  const float* Wk = (const float*)d_in[3];
  const float* bk = (const float*)d_in[4];
  const float* Wv = (const float*)d_in[5];
  const float* bv = (const float*)d_in[6];
  const float* Wo = (const float*)d_in[7];
  const float* bo = (const float*)d_in[8];
  const float* P  = (const float*)d_in[9];
  float* out = (float*)d_out;

  char* ws = (char*)d_ws;
  bf16_t* xb     = (bf16_t*)(ws + 0);            // 32 MB
  bf16_t* QKV    = (bf16_t*)(ws + 33554432);     // 96 MB
  bf16_t* Wcat   = (bf16_t*)(ws + 134217728);    // 6 MB
  float*  bcat   = (float*) (ws + 140509184);    // 12 KB
  float*  kvpart = (float*) (ws + 140521472);    // 8 MB
  float*  kvbuf  = (float*) (ws + 148910080);    // 1 MB
  bf16_t* WcT    = (bf16_t*)(ws + 149958656);    // 8 MB

  // 1. merged casts + weight prep
  prep_misc<<<8705, 256, 0, stream>>>(x, Wv, bv, xb, Wcat + (size_t)2048 * 1024, bcat);
  prep_wqk<<<256, 256, 0, stream>>>(Wq, bq, Wk, bk, P, Wcat, bcat);

  // 2. fused Q'/K'/V GEMM: [16384,1024] x [3072,1024]^T -> [16384,3072]
  //    grid 64 x 12 = 768 blocks (768 % 8 == 0), cpx = 96   (r1-exact)
  gemm256<1><<<768, 512, 0, stream>>>(
      xb, 1024, Wcat, 1024, bcat, QKV, 3072, 1024, 12, 96, 1 << 30, 0);

  // 3. kv = K'^T @ V per (b,h), 8-way split over s, then reduce
  kv_partial<<<dim3(64, 8), 256, 0, stream>>>(QKV, kvpart);
  kv_reduce<<<1024, 256, 0, stream>>>(kvpart, kvbuf);

  // 4. fold kv into Wo: WcombT per batch
  wcombt_kernel<<<dim3(8, 16, 4), 256, 0, stream>>>(kvbuf, Wo, WcT);

  // 5. out = Q' @ WcombT[b]^T + bo  (fp32 out) — 128^2 tile, 2 blocks/CU
  //    grid 128 x 8 = 1024 blocks, cpx = 128
  gemm128<<<1024, 512, 0, stream>>>(
      QKV, 3072, WcT, 1024, bo, out, 1024, 1024, 8, 128, 4096, (long)1024 * 1024);
}

// Round 9
// 231.715 us; speedup vs baseline: 1.3340x; 1.0091x over previous
//
#include <hip/hip_runtime.h>
#include <hip/hip_bf16.h>
#include <cstdint>

typedef __bf16 bf16_t;
typedef bf16_t bf16x8 __attribute__((ext_vector_type(8)));
typedef float f32x4 __attribute__((ext_vector_type(4)));
typedef float f32x16 __attribute__((ext_vector_type(16)));

// B=4, S=4096, DIM=1024, H=16, HD=64, M=64
// QKV layout: [16384][3072] bf16, cols 0-1023 = Q', 1024-2047 = K', 2048-3071 = V

__device__ __forceinline__ void gload_lds16(const bf16_t* g, bf16_t* l) {
  __builtin_amdgcn_global_load_lds(
      (const __attribute__((address_space(1))) uint32_t*)g,
      (__attribute__((address_space(3))) uint32_t*)l, 16, 0, 0);
}

// ---------------- merged prep: cast x, cast Wv, copy bv (one launch) ------------
__global__ void prep_misc(const float* __restrict__ x, const float* __restrict__ Wv,
                          const float* __restrict__ bv,
                          bf16_t* __restrict__ xb, bf16_t* __restrict__ WvO,
                          float* __restrict__ bcat) {
  int b = blockIdx.x, t = threadIdx.x;
  if (b < 8192) {
    long i = (long)b * 256 + t;
    const f32x4* p = (const f32x4*)(x + i * 8);
    f32x4 a = p[0], c = p[1];
    bf16x8 o;
#pragma unroll
    for (int j = 0; j < 4; ++j) { o[j] = (bf16_t)a[j]; o[j + 4] = (bf16_t)c[j]; }
    *(bf16x8*)(xb + i * 8) = o;
  } else if (b < 8704) {
    long i = (long)(b - 8192) * 256 + t;
    const f32x4* p = (const f32x4*)(Wv + i * 8);
    f32x4 a = p[0], c = p[1];
    bf16x8 o;
#pragma unroll
    for (int j = 0; j < 4; ++j) { o[j] = (bf16_t)a[j]; o[j + 4] = (bf16_t)c[j]; }
    *(bf16x8*)(WvO + i * 8) = o;
  } else {
    *(f32x4*)&bcat[2048 + t * 4] = *(const f32x4*)&bv[t * 4];
  }
}

// ---------------- fold P into Wq/Wk:  WQP[h*64+m][k] = sum_d P[h][m][d]*W[h*64+d][k] ----------------
__global__ __launch_bounds__(256) void prep_wqk(
    const float* __restrict__ Wq, const float* __restrict__ bq,
    const float* __restrict__ Wk, const float* __restrict__ bk,
    const float* __restrict__ P,
    bf16_t* __restrict__ Wcat, float* __restrict__ bcat)
{
  int bid = blockIdx.x;
  int qk = bid >> 7, h = (bid >> 3) & 15, kt = bid & 7;
  const float* W = qk ? Wk : Wq;
  const float* bias = qk ? bk : bq;
  __shared__ float Pl[64 * 64];
  __shared__ float Wlt[128 * 68];
  int t = threadIdx.x;
  int k0 = kt * 128;
  for (int i = t * 4; i < 4096; i += 1024)
    *(f32x4*)&Pl[i] = *(const f32x4*)&P[h * 4096 + i];
  for (int fi = t; fi < 2048; fi += 256) {
    int row = fi >> 5;
    int c4 = fi & 31;
    f32x4 w = *(const f32x4*)&W[(long)(h * 64 + row) * 1024 + k0 + c4 * 4];
#pragma unroll
    for (int j = 0; j < 4; ++j) Wlt[(c4 * 4 + j) * 68 + row] = w[j];
  }
  __syncthreads();
  int kloc = t >> 1;
  int mh = (t & 1) * 32;
  for (int m = mh; m < mh + 32; ++m) {
    f32x4 s = {0.f, 0.f, 0.f, 0.f};
#pragma unroll
    for (int dd = 0; dd < 16; ++dd)
      s += (*(const f32x4*)&Pl[m * 64 + dd * 4]) * (*(const f32x4*)&Wlt[kloc * 68 + dd * 4]);
    float a = s[0] + s[1] + s[2] + s[3];
    Wcat[(long)(qk * 1024 + h * 64 + m) * 1024 + k0 + kloc] = (bf16_t)a;
  }
  if (kt == 0 && t < 64) {
    float a = 0.f;
    for (int d = 0; d < 64; ++d) a += Pl[t * 64 + d] * bias[h * 64 + d];
    bcat[qk * 1024 + h * 64 + t] = a;
  }
}

// ---------------- 256x256 GEMM: r1 loop, 32x32x16 MFMA ---------------------------
// C[M,N] = A[M,K] @ B[N,K]^T + bias.  EPI=1: bf16 out, relu*0.125 for gcol<2048.
// EPI=2: fp32 out.
// Per wave 128x64 = 4(mi,32row) x 2(ni,32col) tiles of f32x16.
// A/B frag: row = l&31, k = (l>>5)*8+elem -> LDS chunk kq = 2*kstep + (l>>5),
// addr = row*64 + (kq ^ (row&7))*8 (same XOR involution, measured 0 conflicts).
template <int EPI>
__global__ __launch_bounds__(512, 2) void gemm256(
    const bf16_t* __restrict__ A, int lda,
    const bf16_t* __restrict__ B0, int ldb,
    const float* __restrict__ bias,
    void* __restrict__ Cv, int ldc,
    int K, int ncols, int cpx,
    int rows_per_batch, long bstride)
{
  __shared__ bf16_t sA[2][16384];
  __shared__ bf16_t sB[2][16384];

  const int lin = blockIdx.x;
  const int wgid = (lin & 7) * cpx + (lin >> 3);
  const int row0 = (wgid / ncols) * 256;
  const int col0 = (wgid % ncols) * 256;

  const int tid = threadIdx.x;
  const int w = tid >> 6, l = tid & 63;
  const int wr = w >> 2, wc = w & 3;          // wave grid 2(M) x 4(N)
  const int l31 = l & 31, kh = l >> 5, x7 = l & 7;

  const bf16_t* Bm = B0 + (long)(row0 / rows_per_batch) * bstride;

  long a_off[4], b_off[4];
#pragma unroll
  for (int i = 0; i < 4; ++i) {
    int c = i * 512 + tid;
    int r = c >> 3;
    int kqs = (c & 7) ^ (r & 7);
    a_off[i] = (long)(row0 + r) * lda + kqs * 8;
    b_off[i] = (long)(col0 + r) * ldb + kqs * 8;
  }
  const int ldst = tid * 8;

  // ds_read bases; chunk offset per kstep s: ((2s + kh) ^ x7) * 8
  const int abase = (wr * 128 + l31) * 64;
  const int bbase = (wc * 64 + l31) * 64;
  const int e0 = ((0 + kh) ^ x7) * 8;   // kstep 0
  const int e1 = ((2 + kh) ^ x7) * 8;   // kstep 1
  const int e2 = ((4 + kh) ^ x7) * 8;   // kstep 2
  const int e3 = ((6 + kh) ^ x7) * 8;   // kstep 3

  f32x16 acc[4][2] = {};
  const int NT = K >> 6;

#pragma unroll
  for (int i = 0; i < 4; ++i) {
    gload_lds16(A + a_off[i], &sA[0][i * 4096 + ldst]);
    gload_lds16(Bm + b_off[i], &sB[0][i * 4096 + ldst]);
  }
  __syncthreads();

#define TILE_BODY(PC, PN, T)                                                            \
  {                                                                                     \
    bf16x8 afr[4][2], bfr[2][2];                                                        \
    _Pragma("unroll") for (int mi = 0; mi < 4; ++mi) {                                  \
      afr[mi][0] = *(const bf16x8*)&sA[PC][abase + mi * 2048 + e0];                     \
      afr[mi][1] = *(const bf16x8*)&sA[PC][abase + mi * 2048 + e1];                     \
    }                                                                                   \
    _Pragma("unroll") for (int ni = 0; ni < 2; ++ni) {                                  \
      bfr[ni][0] = *(const bf16x8*)&sB[PC][bbase + ni * 2048 + e0];                     \
      bfr[ni][1] = *(const bf16x8*)&sB[PC][bbase + ni * 2048 + e1];                     \
    }                                                                                   \
    if ((T) + 1 < NT) {                                                                 \
      long ks = (long)((T) + 1) * 64;                                                   \
      _Pragma("unroll") for (int i = 0; i < 4; ++i) {                                   \
        gload_lds16(A + a_off[i] + ks, &sA[PN][i * 4096 + ldst]);                       \
        gload_lds16(Bm + b_off[i] + ks, &sB[PN][i * 4096 + ldst]);                      \
      }                                                                                 \
    }                                                                                   \
    __builtin_amdgcn_s_setprio(1);                                                      \
    _Pragma("unroll") for (int mi = 0; mi < 4; ++mi)                                    \
      _Pragma("unroll") for (int ni = 0; ni < 2; ++ni) {                                \
        acc[mi][ni] = __builtin_amdgcn_mfma_f32_32x32x16_bf16(afr[mi][0], bfr[ni][0], acc[mi][ni], 0, 0, 0); \
        acc[mi][ni] = __builtin_amdgcn_mfma_f32_32x32x16_bf16(afr[mi][1], bfr[ni][1], acc[mi][ni], 0, 0, 0); \
      }                                                                                 \
    __builtin_amdgcn_s_setprio(0);                                                      \
    _Pragma("unroll") for (int mi = 0; mi < 4; ++mi) {                                  \
      afr[mi][0] = *(const bf16x8*)&sA[PC][abase + mi * 2048 + e2];                     \
      afr[mi][1] = *(const bf16x8*)&sA[PC][abase + mi * 2048 + e3];                     \
    }                                                                                   \
    _Pragma("unroll") for (int ni = 0; ni < 2; ++ni) {                                  \
      bfr[ni][0] = *(const bf16x8*)&sB[PC][bbase + ni * 2048 + e2];                     \
      bfr[ni][1] = *(const bf16x8*)&sB[PC][bbase + ni * 2048 + e3];                     \
    }                                                                                   \
    __builtin_amdgcn_s_setprio(1);                                                      \
    _Pragma("unroll") for (int mi = 0; mi < 4; ++mi)                                    \
      _Pragma("unroll") for (int ni = 0; ni < 2; ++ni) {                                \
        acc[mi][ni] = __builtin_amdgcn_mfma_f32_32x32x16_bf16(afr[mi][0], bfr[ni][0], acc[mi][ni], 0, 0, 0); \
        acc[mi][ni] = __builtin_amdgcn_mfma_f32_32x32x16_bf16(afr[mi][1], bfr[ni][1], acc[mi][ni], 0, 0, 0); \
      }                                                                                 \
    __builtin_amdgcn_s_setprio(0);                                                      \
    __syncthreads();                                                                    \
  }

  for (int t = 0; t < NT; t += 2) {
    TILE_BODY(0, 1, t);
    TILE_BODY(1, 0, t + 1);
  }
#undef TILE_BODY

  // epilogue: 32x32 C/D layout col=lane&31, row=(reg&3)+8*(reg>>2)+4*(lane>>5)
#pragma unroll
  for (int ni = 0; ni < 2; ++ni) {
    const int gcol = col0 + wc * 64 + ni * 32 + l31;
    const float bz = bias[gcol];
    const bool doRelu = (EPI == 1) && (gcol < 2048);
#pragma unroll
    for (int mi = 0; mi < 4; ++mi) {
      const int rbase = row0 + wr * 128 + mi * 32 + 4 * kh;
#pragma unroll
      for (int reg = 0; reg < 16; ++reg) {
        const int grow = rbase + (reg & 3) + 8 * (reg >> 2);
        float v = acc[mi][ni][reg] + bz;
        if constexpr (EPI == 1) { if (doRelu) v = fmaxf(v, 0.f) * 0.125f; }
        if constexpr (EPI == 2)
          ((float*)Cv)[(long)grow * ldc + gcol] = v;
        else
          ((bf16_t*)Cv)[(long)grow * ldc + gcol] = (bf16_t)v;
      }
    }
  }
}

// ---------------- 128x128 GEMM: same loop, 32x32x16, 64KB LDS, 2 blocks/CU -------
// fp32 out + bias. Wave grid 2M x 4N, per-wave 64x32 = 2 tiles of 32x32.
__global__ __launch_bounds__(512, 4) void gemm128(
    const bf16_t* __restrict__ A, int lda,
    const bf16_t* __restrict__ B0, int ldb,
    const float* __restrict__ bias,
    float* __restrict__ C, int ldc,
    int K, int ncols, int cpx,
    int rows_per_batch, long bstride)
{
  __shared__ bf16_t sA[2][8192];
  __shared__ bf16_t sB[2][8192];

  const int lin = blockIdx.x;
  const int wgid = (lin & 7) * cpx + (lin >> 3);
  const int row0 = (wgid / ncols) * 128;
  const int col0 = (wgid % ncols) * 128;

  const int tid = threadIdx.x;
  const int w = tid >> 6, l = tid & 63;
  const int wr = w >> 2, wc = w & 3;
  const int l31 = l & 31, kh = l >> 5, x7 = l & 7;

  const bf16_t* Bm = B0 + (long)(row0 / rows_per_batch) * bstride;

  long a_off[2], b_off[2];
#pragma unroll
  for (int i = 0; i < 2; ++i) {
    int c = i * 512 + tid;
    int r = c >> 3;
    int kqs = (c & 7) ^ (r & 7);
    a_off[i] = (long)(row0 + r) * lda + kqs * 8;
    b_off[i] = (long)(col0 + r) * ldb + kqs * 8;
  }
  const int ldst = tid * 8;

  const int abase = (wr * 64 + l31) * 64;
  const int bbase = (wc * 32 + l31) * 64;
  const int e0 = ((0 + kh) ^ x7) * 8;
  const int e1 = ((2 + kh) ^ x7) * 8;
  const int e2 = ((4 + kh) ^ x7) * 8;
  const int e3 = ((6 + kh) ^ x7) * 8;

  f32x16 acc[2] = {};
  const int NT = K >> 6;

#pragma unroll
  for (int i = 0; i < 2; ++i) {
    gload_lds16(A + a_off[i], &sA[0][i * 4096 + ldst]);
    gload_lds16(Bm + b_off[i], &sB[0][i * 4096 + ldst]);
  }
  __syncthreads();

#define TILE128(PC, PN, T)                                                              \
  {                                                                                     \
    bf16x8 afr[2][2], bfr[2];                                                           \
    _Pragma("unroll") for (int mi = 0; mi < 2; ++mi) {                                  \
      afr[mi][0] = *(const bf16x8*)&sA[PC][abase + mi * 2048 + e0];                     \
      afr[mi][1] = *(const bf16x8*)&sA[PC][abase + mi * 2048 + e1];                     \
    }                                                                                   \
    bfr[0] = *(const bf16x8*)&sB[PC][bbase + e0];                                       \
    bfr[1] = *(const bf16x8*)&sB[PC][bbase + e1];                                       \
    if ((T) + 1 < NT) {                                                                 \
      long ks = (long)((T) + 1) * 64;                                                   \
      _Pragma("unroll") for (int i = 0; i < 2; ++i) {                                   \
        gload_lds16(A + a_off[i] + ks, &sA[PN][i * 4096 + ldst]);                       \
        gload_lds16(Bm + b_off[i] + ks, &sB[PN][i * 4096 + ldst]);                      \
      }                                                                                 \
    }                                                                                   \
    __builtin_amdgcn_s_setprio(1);                                                      \
    _Pragma("unroll") for (int mi = 0; mi < 2; ++mi) {                                  \
      acc[mi] = __builtin_amdgcn_mfma_f32_32x32x16_bf16(afr[mi][0], bfr[0], acc[mi], 0, 0, 0); \
      acc[mi] = __builtin_amdgcn_mfma_f32_32x32x16_bf16(afr[mi][1], bfr[1], acc[mi], 0, 0, 0); \
    }                                                                                   \
    __builtin_amdgcn_s_setprio(0);                                                      \
    _Pragma("unroll") for (int mi = 0; mi < 2; ++mi) {                                  \
      afr[mi][0] = *(const bf16x8*)&sA[PC][abase + mi * 2048 + e2];                     \
      afr[mi][1] = *(const bf16x8*)&sA[PC][abase + mi * 2048 + e3];                     \
    }                                                                                   \
    bfr[0] = *(const bf16x8*)&sB[PC][bbase + e2];                                       \
    bfr[1] = *(const bf16x8*)&sB[PC][bbase + e3];                                       \
    __builtin_amdgcn_s_setprio(1);                                                      \
    _Pragma("unroll") for (int mi = 0; mi < 2; ++mi) {                                  \
      acc[mi] = __builtin_amdgcn_mfma_f32_32x32x16_bf16(afr[mi][0], bfr[0], acc[mi], 0, 0, 0); \
      acc[mi] = __builtin_amdgcn_mfma_f32_32x32x16_bf16(afr[mi][1], bfr[1], acc[mi], 0, 0, 0); \
    }                                                                                   \
    __builtin_amdgcn_s_setprio(0);                                                      \
    __syncthreads();                                                                    \
  }

  for (int t = 0; t < NT; t += 2) {
    TILE128(0, 1, t);
    TILE128(1, 0, t + 1);
  }
#undef TILE128

  const int gcol = col0 + wc * 32 + l31;
  const float bz = bias[gcol];
#pragma unroll
  for (int mi = 0; mi < 2; ++mi) {
    const int rbase = row0 + wr * 64 + mi * 32 + 4 * kh;
#pragma unroll
    for (int reg = 0; reg < 16; ++reg) {
      const int grow = rbase + (reg & 3) + 8 * (reg >> 2);
      C[(long)grow * ldc + gcol] = acc[mi][reg] + bz;
    }
  }
}

// ---------------- kv partial: kv[b,h,m,d] = sum_s K'[b,s,h,m]*V[b,s,h,d] ----------------
__global__ __launch_bounds__(256) void kv_partial(
    const bf16_t* __restrict__ QKV, float* __restrict__ kvpart)
{
  int bh = blockIdx.x;
  int split = blockIdx.y;
  int b = bh >> 4, h = bh & 15;
  __shared__ alignas(16) bf16_t Kt[64 * 32];
  __shared__ alignas(16) bf16_t Vt[64 * 32];
  int t = threadIdx.x;
  int wv = t >> 6, lane = t & 63, lhi = lane >> 4, llo = lane & 15;
  int r = t >> 3;
  int c = (t & 7) * 8;
  f32x4 acc[4] = {};
  long rowbase = ((long)b * 4096 + split * 512) * 3072 + h * 64 + c;
  for (int sc = 0; sc < 16; ++sc) {
    long off = rowbase + (long)(sc * 32 + r) * 3072;
    bf16x8 kk = *(const bf16x8*)(QKV + off + 1024);
    bf16x8 vvv = *(const bf16x8*)(QKV + off + 2048);
#pragma unroll
    for (int j = 0; j < 8; ++j) {
      Kt[(c + j) * 32 + r] = kk[j];
      Vt[(c + j) * 32 + r] = vvv[j];
    }
    __syncthreads();
    bf16x8 a = *(const bf16x8*)&Kt[(wv * 16 + llo) * 32 + lhi * 8];
#pragma unroll
    for (int ni = 0; ni < 4; ++ni) {
      bf16x8 bb = *(const bf16x8*)&Vt[(ni * 16 + llo) * 32 + lhi * 8];
      acc[ni] = __builtin_amdgcn_mfma_f32_16x16x32_bf16(a, bb, acc[ni], 0, 0, 0);
    }
    __syncthreads();
  }
#pragma unroll
  for (int ni = 0; ni < 4; ++ni)
#pragma unroll
    for (int j = 0; j < 4; ++j) {
      int m = wv * 16 + lhi * 4 + j;
      int d = ni * 16 + llo;
      kvpart[((long)split * 64 + bh) * 4096 + m * 64 + d] = acc[ni][j];
    }
}

__global__ void kv_reduce(const float* __restrict__ part, float* __restrict__ kv) {
  int i = blockIdx.x * 256 + threadIdx.x;
  float s = 0.f;
#pragma unroll
  for (int sp = 0; sp < 8; ++sp) s += part[sp * 262144 + i];
  kv[i] = s;
}

// ---------------- WcombT[b][n][h*64+m] = sum_d kv[b,h,m,d] * Wo[n][h*64+d] ----------------
__global__ __launch_bounds__(256) void wcombt_kernel(
    const float* __restrict__ kv, const float* __restrict__ Wo,
    bf16_t* __restrict__ WcT)
{
  int nt = blockIdx.x, h = blockIdx.y, b = blockIdx.z;
  __shared__ float kvs[4096];
  int t = threadIdx.x;
  for (int i = t * 4; i < 4096; i += 1024)
    *(f32x4*)&kvs[i] = *(const f32x4*)&kv[((long)b * 16 + h) * 4096 + i];
  __syncthreads();
  int n = nt * 128 + (t >> 1);
  int mh = (t & 1) * 32;
  f32x4 wo[16];
#pragma unroll
  for (int dd = 0; dd < 16; ++dd) wo[dd] = *(const f32x4*)&Wo[(long)n * 1024 + h * 64 + dd * 4];
  for (int m = mh; m < mh + 32; ++m) {
    f32x4 s = {0.f, 0.f, 0.f, 0.f};
#pragma unroll
    for (int dd = 0; dd < 16; ++dd)
      s += (*(const f32x4*)&kvs[m * 64 + dd * 4]) * wo[dd];
    WcT[((long)b * 1024 + n) * 1024 + h * 64 + m] = (bf16_t)(s[0] + s[1] + s[2] + s[3]);
  }
}

// ---------------- launch ----------------
extern "C" void kernel_launch(void* const* d_in, const int* in_sizes, int n_in,
                              void* d_out, int out_size, void* d_ws, size_t ws_size,
                              hipStream_t stream) {
  (void)in_sizes; (void)n_in; (void)out_size; (void)ws_size;
  const float* x  = (const float*)d_in[0];
  const float* Wq = (const float*)d_in[1];
  const float* bq = (const float*)d_in[2];
  const float* Wk = (const float*)d_in[3];
  const float* bk = (const float*)d_in[4];
  const float* Wv = (const float*)d_in[5];
  const float* bv = (const float*)d_in[6];
  const float* Wo = (const float*)d_in[7];
  const float* bo = (const float*)d_in[8];
  const float* P  = (const float*)d_in[9];
  float* out = (float*)d_out;

  char* ws = (char*)d_ws;
  bf16_t* xb     = (bf16_t*)(ws + 0);            // 32 MB
  bf16_t* QKV    = (bf16_t*)(ws + 33554432);     // 96 MB
  bf16_t* Wcat   = (bf16_t*)(ws + 134217728);    // 6 MB
  float*  bcat   = (float*) (ws + 140509184);    // 12 KB
  float*  kvpart = (float*) (ws + 140521472);    // 8 MB
  float*  kvbuf  = (float*) (ws + 148910080);    // 1 MB
  bf16_t* WcT    = (bf16_t*)(ws + 149958656);    // 8 MB

  // 1. merged casts + weight prep
  prep_misc<<<8705, 256, 0, stream>>>(x, Wv, bv, xb, Wcat + (size_t)2048 * 1024, bcat);
  prep_wqk<<<256, 256, 0, stream>>>(Wq, bq, Wk, bk, P, Wcat, bcat);

  // 2. fused Q'/K'/V GEMM: [16384,1024] x [3072,1024]^T -> [16384,3072]
  //    grid 64 x 12 = 768 blocks, cpx = 96
  gemm256<1><<<768, 512, 0, stream>>>(
      xb, 1024, Wcat, 1024, bcat, QKV, 3072, 1024, 12, 96, 1 << 30, 0);

  // 3. kv = K'^T @ V per (b,h), 8-way split over s, then reduce
  kv_partial<<<dim3(64, 8), 256, 0, stream>>>(QKV, kvpart);
  kv_reduce<<<1024, 256, 0, stream>>>(kvpart, kvbuf);

  // 4. fold kv into Wo: WcombT per batch
  wcombt_kernel<<<dim3(8, 16, 4), 256, 0, stream>>>(kvbuf, Wo, WcT);

  // 5. out = Q' @ WcombT[b]^T + bo  (fp32 out) — 128^2 tile
  //    grid 128 x 8 = 1024 blocks, cpx = 128
  gemm128<<<1024, 512, 0, stream>>>(
      QKV, 3072, WcT, 1024, bo, out, 1024, 1024, 8, 128, 4096, (long)1024 * 1024);
}